// Round 2
// baseline (2792.103 us; speedup 1.0000x reference)
//
#include <hip/hip_runtime.h>

// ---------- types ----------
typedef float  f32x4  __attribute__((ext_vector_type(4)));
typedef __bf16 bf16x8 __attribute__((ext_vector_type(8)));

static __device__ __forceinline__ unsigned short f2bf(float f) {
  unsigned int u = __builtin_bit_cast(unsigned int, f);
  u += 0x7fffu + ((u >> 16) & 1u);   // RNE
  return (unsigned short)(u >> 16);
}

// ---------- copy past_k/past_v into output cache regions ----------
// out float4-index: k region starts at 8192 (=32768/4), v region +524288.
__global__ __launch_bounds__(256) void copy_past_kernel(
    const float4* __restrict__ pk, const float4* __restrict__ pv,
    float4* __restrict__ out4)
{
  const int id  = blockIdx.x * 256 + threadIdx.x;    // 0..524287
  const int t4  = id & 262143;
  const int isv = id >> 18;
  const float4 v = (isv ? pv : pk)[t4];
  const int d4   = t4 & 15;
  const int t    = (t4 >> 4) & 1023;
  const int gidx = t4 >> 14;                         // l*8+kvh, 0..15
  const size_t dst = 8192 + ((size_t)gidx * 2048 + t) * 16 + d4 + (size_t)isv * 524288;
  out4[dst] = v;
}

// ---------- RMSNorm (per-row) -> bf16 ----------
__global__ __launch_bounds__(256) void rms_kernel(
    const float* __restrict__ x, const float* __restrict__ w,
    unsigned short* __restrict__ out)
{
  const int row = blockIdx.x;
  const int tid = threadIdx.x;
  const float4* xr = (const float4*)(x + (size_t)row * 2048);
  const float4 a = xr[tid], b = xr[tid + 256];
  float ss = a.x*a.x + a.y*a.y + a.z*a.z + a.w*a.w
           + b.x*b.x + b.y*b.y + b.z*b.z + b.w*b.w;
  #pragma unroll
  for (int o = 32; o > 0; o >>= 1) ss += __shfl_xor(ss, o);
  __shared__ float sred[4];
  if ((tid & 63) == 0) sred[tid >> 6] = ss;
  __syncthreads();
  const float scale = rsqrtf((sred[0]+sred[1]+sred[2]+sred[3]) * (1.f/2048.f) + 1e-6f);
  const float4* wr = (const float4*)w;
  const float4 w0 = wr[tid], w1 = wr[tid + 256];
  uint2 p0, p1;
  p0.x = f2bf(a.x*scale*w0.x) | ((unsigned)f2bf(a.y*scale*w0.y) << 16);
  p0.y = f2bf(a.z*scale*w0.z) | ((unsigned)f2bf(a.w*scale*w0.w) << 16);
  p1.x = f2bf(b.x*scale*w1.x) | ((unsigned)f2bf(b.y*scale*w1.y) << 16);
  p1.y = f2bf(b.z*scale*w1.z) | ((unsigned)f2bf(b.w*scale*w1.w) << 16);
  uint2* op = (uint2*)(out + (size_t)row * 2048);
  op[tid] = p0;
  op[tid + 256] = p1;
}

// ---------- final RMSNorm on last row -> f32 ----------
__global__ __launch_bounds__(256) void rms_last_kernel(
    const float* __restrict__ h, const float* __restrict__ w,
    float* __restrict__ out)
{
  const int tid = threadIdx.x;
  const float4* xr = (const float4*)(h + (size_t)1023 * 2048);
  const float4 a = xr[tid], b = xr[tid + 256];
  float ss = a.x*a.x + a.y*a.y + a.z*a.z + a.w*a.w
           + b.x*b.x + b.y*b.y + b.z*b.z + b.w*b.w;
  #pragma unroll
  for (int o = 32; o > 0; o >>= 1) ss += __shfl_xor(ss, o);
  __shared__ float sred[4];
  if ((tid & 63) == 0) sred[tid >> 6] = ss;
  __syncthreads();
  const float scale = rsqrtf((sred[0]+sred[1]+sred[2]+sred[3]) * (1.f/2048.f) + 1e-6f);
  const float4* wr = (const float4*)w;
  const float4 w0 = wr[tid], w1 = wr[tid + 256];
  float4 r0, r1;
  r0.x = a.x*scale*w0.x; r0.y = a.y*scale*w0.y; r0.z = a.z*scale*w0.z; r0.w = a.w*scale*w0.w;
  r1.x = b.x*scale*w1.x; r1.y = b.y*scale*w1.y; r1.z = b.z*scale*w1.z; r1.w = b.w*scale*w1.w;
  ((float4*)out)[tid] = r0;
  ((float4*)out)[tid + 256] = r1;
}

// ---------- generic MFMA GEMM: C[M,N] = A(bf16)[M,K] @ B(f32->bf16)[K,N] ----------
// EPI 0: store f32. EPI 1: C += acc (residual, in place). EPI 2: v-cache scatter.
template<int BM, int BN, int EPI>
__global__ __launch_bounds__(256) void gemm_k(
    const unsigned short* __restrict__ A,
    const float* __restrict__ B,
    float* __restrict__ C,
    const int M, const int N, const int K)
{
  constexpr int WM = BM / 2, WN = BN / 2, MF = WM / 16, NF = WN / 16;
  __shared__ unsigned short As[BM * 64];   // [row][64k], 128B rows, XOR-swizzled
  __shared__ unsigned short Bs[BN * 64];   // [col][64k] (B^T), same swizzle
  const int tid  = threadIdx.x;
  const int lane = tid & 63;
  const int wave = tid >> 6;
  const int bn0  = blockIdx.x * BN;
  const int m0   = blockIdx.y * BM;
  const int wm0  = (wave >> 1) * WM;
  const int wn0  = (wave & 1) * WN;

  f32x4 acc[MF][NF];
  #pragma unroll
  for (int i = 0; i < MF; ++i)
    #pragma unroll
    for (int j = 0; j < NF; ++j)
      #pragma unroll
      for (int r = 0; r < 4; ++r) acc[i][j][r] = 0.f;

  const int nkt = K >> 6;
  for (int kt = 0; kt < nkt; ++kt) {
    const int k0 = kt << 6;
    // --- stage A (already bf16): 16B per thread per pass ---
    #pragma unroll
    for (int p = 0; p < BM / 32; ++p) {
      const int idx = p * 256 + tid;
      const int row = idx >> 3, ch = idx & 7;
      const int4 v = *(const int4*)(A + (size_t)(m0 + row) * K + (k0 + ch * 8));
      *(int4*)((char*)As + (row * 128 + ((ch * 16) ^ ((row & 7) << 4)))) = v;
    }
    // --- stage B (f32 -> bf16, transpose to [n][k]): 8 coalesced scalar loads ---
    #pragma unroll
    for (int p = 0; p < BN / 32; ++p) {
      const int idx = p * 256 + tid;
      const int n  = idx & (BN - 1);
      const int kg = idx >> (BN == 64 ? 6 : 7);
      const float* src = B + (size_t)(k0 + kg * 8) * N + (bn0 + n);
      const float f0 = src[0];
      const float f1 = src[(size_t)N];
      const float f2 = src[(size_t)2 * N];
      const float f3 = src[(size_t)3 * N];
      const float f4 = src[(size_t)4 * N];
      const float f5 = src[(size_t)5 * N];
      const float f6 = src[(size_t)6 * N];
      const float f7 = src[(size_t)7 * N];
      int4 pk;
      pk.x = f2bf(f0) | ((unsigned)f2bf(f1) << 16);
      pk.y = f2bf(f2) | ((unsigned)f2bf(f3) << 16);
      pk.z = f2bf(f4) | ((unsigned)f2bf(f5) << 16);
      pk.w = f2bf(f6) | ((unsigned)f2bf(f7) << 16);
      *(int4*)((char*)Bs + (n * 128 + ((kg * 16) ^ ((n & 7) << 4)))) = pk;
    }
    __syncthreads();
    // --- compute: 2 k-steps of K=32 ---
    #pragma unroll
    for (int ks = 0; ks < 2; ++ks) {
      bf16x8 af[MF], bfr[NF];
      const int r = lane & 15;
      const int kbyte = ((lane >> 4) << 4) + ks * 64;
      #pragma unroll
      for (int i = 0; i < MF; ++i) {
        const int row = wm0 + i * 16 + r;
        af[i] = *(const bf16x8*)((const char*)As + (row * 128 + (kbyte ^ ((row & 7) << 4))));
      }
      #pragma unroll
      for (int j = 0; j < NF; ++j) {
        const int col = wn0 + j * 16 + r;
        bfr[j] = *(const bf16x8*)((const char*)Bs + (col * 128 + (kbyte ^ ((col & 7) << 4))));
      }
      #pragma unroll
      for (int i = 0; i < MF; ++i)
        #pragma unroll
        for (int j = 0; j < NF; ++j)
          acc[i][j] = __builtin_amdgcn_mfma_f32_16x16x32_bf16(af[i], bfr[j], acc[i][j], 0, 0, 0);
    }
    __syncthreads();
  }

  // --- epilogue (C/D layout: col = lane&15, row = (lane>>4)*4 + reg) ---
  #pragma unroll
  for (int i = 0; i < MF; ++i) {
    #pragma unroll
    for (int j = 0; j < NF; ++j) {
      #pragma unroll
      for (int rr = 0; rr < 4; ++rr) {
        const int row = m0 + wm0 + i * 16 + ((lane >> 4) << 2) + rr;
        const int col = bn0 + wn0 + j * 16 + (lane & 15);
        const float val = acc[i][j][rr];
        if (EPI == 0)      C[(size_t)row * N + col] = val;
        else if (EPI == 1) C[(size_t)row * N + col] += val;
        else               C[(size_t)(col >> 6) * 131072 + 65536 + (size_t)row * 64 + (col & 63)] = val;
      }
    }
  }
}

// ---------- rotary ----------
__global__ __launch_bounds__(256) void rope_q_kernel(
    float* __restrict__ q, const float* __restrict__ cosT, const float* __restrict__ sinT)
{
  const int id = blockIdx.x * 256 + threadIdx.x;   // 1024*32*32
  const int d  = id & 31;
  const int hh = (id >> 5) & 31;
  const int s  = id >> 10;
  float* qp = q + (size_t)s * 2048 + hh * 64;
  const float c  = cosT[(size_t)(1024 + s) * 64 + d];
  const float sn = sinT[(size_t)(1024 + s) * 64 + d];
  const float a = qp[d], b = qp[d + 32];
  qp[d]      = a * c - b * sn;
  qp[d + 32] = b * c + a * sn;
}

__global__ __launch_bounds__(256) void rope_k_kernel(
    const float* __restrict__ kb, const float* __restrict__ cosT,
    const float* __restrict__ sinT, float* __restrict__ outk_l)
{
  const int id = blockIdx.x * 256 + threadIdx.x;   // 1024*8*32
  const int d  = id & 31;
  const int kh = (id >> 5) & 7;
  const int s  = id >> 8;
  const float* kp = kb + (size_t)s * 512 + kh * 64;
  const float c  = cosT[(size_t)(1024 + s) * 64 + d];
  const float sn = sinT[(size_t)(1024 + s) * 64 + d];
  const float a = kp[d], b = kp[d + 32];
  float* op = outk_l + (size_t)kh * 131072 + (size_t)(1024 + s) * 64;
  op[d]      = a * c - b * sn;
  op[d + 32] = b * c + a * sn;
}

// ---------- flash attention (fp32), causal mask: row s sees kv <= s ----------
__global__ __launch_bounds__(256) void attn_kernel(
    const float* __restrict__ q,
    const float* __restrict__ Kc,   // layer base [8][2048][64]
    const float* __restrict__ Vc,
    unsigned short* __restrict__ ctx,
    const int* __restrict__ flagp)
{
  const int tid = threadIdx.x;
  const int r   = tid & 31;      // q-row within block
  const int c   = tid >> 5;      // kv chunk 0..7 (256 kv each)
  const int qb  = blockIdx.x;    // 0..31
  const int hh  = blockIdx.y;    // 0..31
  const int s   = qb * 32 + r;
  const int kvh = hh >> 2;       // groups = 4
  const int flag = *flagp;
  const int limit = flag ? s : 2047;
  const float* qp = q + (size_t)s * 2048 + hh * 64;
  float4 qr[16];
  #pragma unroll
  for (int i = 0; i < 16; ++i) qr[i] = ((const float4*)qp)[i];
  const float* Kb = Kc + (size_t)kvh * 131072;
  const float* Vb = Vc + (size_t)kvh * 131072;
  float m = -1e30f, l = 0.f;
  float4 acc[16];
  #pragma unroll
  for (int i = 0; i < 16; ++i) { acc[i].x = 0.f; acc[i].y = 0.f; acc[i].z = 0.f; acc[i].w = 0.f; }
  const int t0   = c * 256;
  const int tend = (t0 + 256 < limit + 1) ? (t0 + 256) : (limit + 1);
  for (int t = t0; t < tend; ++t) {
    const float4* kr = (const float4*)(Kb + (size_t)t * 64);
    float d0 = 0.f, d1 = 0.f, d2 = 0.f, d3 = 0.f;
    #pragma unroll
    for (int i = 0; i < 16; ++i) {
      const float4 kk = kr[i];
      d0 = fmaf(qr[i].x, kk.x, d0);
      d1 = fmaf(qr[i].y, kk.y, d1);
      d2 = fmaf(qr[i].z, kk.z, d2);
      d3 = fmaf(qr[i].w, kk.w, d3);
    }
    const float sc = ((d0 + d1) + (d2 + d3)) * 0.125f;
    if (sc > m) {
      const float corr = __expf(m - sc);
      m = sc;
      l *= corr;
      #pragma unroll
      for (int i = 0; i < 16; ++i) {
        acc[i].x *= corr; acc[i].y *= corr; acc[i].z *= corr; acc[i].w *= corr;
      }
    }
    const float p = __expf(sc - m);
    l += p;
    const float4* vr = (const float4*)(Vb + (size_t)t * 64);
    #pragma unroll
    for (int i = 0; i < 16; ++i) {
      const float4 vv = vr[i];
      acc[i].x = fmaf(p, vv.x, acc[i].x);
      acc[i].y = fmaf(p, vv.y, acc[i].y);
      acc[i].z = fmaf(p, vv.z, acc[i].z);
      acc[i].w = fmaf(p, vv.w, acc[i].w);
    }
  }
  // combine 8 chunks per row
  __shared__ float ml[32][8][2];
  __shared__ float outb[32][64];
  __shared__ float Lrow[32];
  ml[r][c][0] = m;
  ml[r][c][1] = l;
  for (int i = tid; i < 2048; i += 256) ((float*)outb)[i] = 0.f;
  __syncthreads();
  float M = -1e30f;
  #pragma unroll
  for (int cc = 0; cc < 8; ++cc) M = fmaxf(M, ml[r][cc][0]);
  float L = 0.f;
  #pragma unroll
  for (int cc = 0; cc < 8; ++cc) L += ml[r][cc][1] * __expf(ml[r][cc][0] - M);
  if (c == 0) Lrow[r] = L;
  const float wgt = __expf(m - M);
  for (int cc = 0; cc < 8; ++cc) {
    if (c == cc) {
      #pragma unroll
      for (int i = 0; i < 16; ++i) {
        outb[r][i * 4 + 0] += acc[i].x * wgt;
        outb[r][i * 4 + 1] += acc[i].y * wgt;
        outb[r][i * 4 + 2] += acc[i].z * wgt;
        outb[r][i * 4 + 3] += acc[i].w * wgt;
      }
    }
    __syncthreads();
  }
  for (int i = tid; i < 2048; i += 256) {
    const int rr = i >> 6, d = i & 63;
    ctx[(size_t)(qb * 32 + rr) * 2048 + (size_t)hh * 64 + d] = f2bf(outb[rr][d] / Lrow[rr]);
  }
}

// ---------- silu(g)*u -> bf16 ----------
__global__ __launch_bounds__(256) void silu_kernel(
    const float* __restrict__ g, const float* __restrict__ u,
    unsigned short* __restrict__ act)
{
  const size_t id = (size_t)blockIdx.x * 256 + threadIdx.x;   // per 4 elems
  const float4 g4 = ((const float4*)g)[id];
  const float4 u4 = ((const float4*)u)[id];
  const float r0 = g4.x * u4.x / (1.f + __expf(-g4.x));
  const float r1 = g4.y * u4.y / (1.f + __expf(-g4.y));
  const float r2 = g4.z * u4.z / (1.f + __expf(-g4.z));
  const float r3 = g4.w * u4.w / (1.f + __expf(-g4.w));
  uint2 o;
  o.x = f2bf(r0) | ((unsigned)f2bf(r1) << 16);
  o.y = f2bf(r2) | ((unsigned)f2bf(r3) << 16);
  ((uint2*)act)[id] = o;
}

// ---------- lm_head GEMV: logits[v] = sum_k hlast[k]*W[k][v] ----------
__global__ __launch_bounds__(256) void gemv_kernel(
    const float* __restrict__ hl_in, const float* __restrict__ W,
    float* __restrict__ out)
{
  __shared__ float hl[2048];
  for (int i = threadIdx.x; i < 2048; i += 256) hl[i] = hl_in[i];
  __syncthreads();
  const int col = blockIdx.x * 128 + (threadIdx.x & 127);
  const int kh  = threadIdx.x >> 7;
  const float* Wp = W + (size_t)kh * 1024 * 32768 + col;
  const float* hp = hl + kh * 1024;
  float acc = 0.f;
  #pragma unroll 8
  for (int k = 0; k < 1024; ++k) acc = fmaf(hp[k], Wp[(size_t)k * 32768], acc);
  __shared__ float part[256];
  part[threadIdx.x] = acc;
  __syncthreads();
  if (threadIdx.x < 128) out[col] = part[threadIdx.x] + part[threadIdx.x + 128];
}

// ---------- launch ----------
extern "C" void kernel_launch(void* const* d_in, const int* in_sizes, int n_in,
                              void* d_out, int out_size, void* d_ws, size_t ws_size,
                              hipStream_t stream)
{
  (void)in_sizes; (void)n_in; (void)out_size; (void)ws_size;
  const float* hidden = (const float*)d_in[0];
  const float* past_k = (const float*)d_in[1];
  const float* past_v = (const float*)d_in[2];
  const float* ln1    = (const float*)d_in[3];
  const float* ln2    = (const float*)d_in[4];
  const float* wq     = (const float*)d_in[5];
  const float* wk     = (const float*)d_in[6];
  const float* wv     = (const float*)d_in[7];
  const float* wo     = (const float*)d_in[8];
  const float* wg     = (const float*)d_in[9];
  const float* wu     = (const float*)d_in[10];
  const float* wd     = (const float*)d_in[11];
  const float* norm_w = (const float*)d_in[12];
  const float* lmh    = (const float*)d_in[13];
  const float* cosT   = (const float*)d_in[14];
  const float* sinT   = (const float*)d_in[15];
  const int*   flagp  = (const int*)d_in[16];

  float* out  = (float*)d_out;
  float* outk = out + 32768;
  float* outv = outk + 2097152;

  float* h            = (float*)d_ws;                        // 1024x2048 f32
  unsigned short* hn  = (unsigned short*)(h + 2097152);      // 1024x2048 bf16
  float* q            = (float*)(hn + 2097152);              // 1024x2048 f32
  float* kb           = q + 2097152;                         // 1024x512  f32
  unsigned short* ctx = (unsigned short*)(kb + 524288);      // 1024x2048 bf16
  float* g            = (float*)(ctx + 2097152);             // 1024x8192 f32
  float* u            = g + 8388608;                         // 1024x8192 f32
  unsigned short* act = (unsigned short*)(u + 8388608);      // 1024x8192 bf16
  float* hlast        = (float*)(act + 8388608);             // 2048 f32

  hipMemcpyAsync(h, hidden, (size_t)2097152 * 4, hipMemcpyDeviceToDevice, stream);
  copy_past_kernel<<<2048, 256, 0, stream>>>((const float4*)past_k, (const float4*)past_v, (float4*)out);

  for (int l = 0; l < 2; ++l) {
    float* outk_l = outk + (size_t)l * 1048576;
    float* outv_l = outv + (size_t)l * 1048576;
    rms_kernel<<<1024, 256, 0, stream>>>(h, ln1 + (size_t)l * 2048, hn);
    gemm_k<128, 64, 0><<<dim3(32, 8), 256, 0, stream>>>(hn, wq + (size_t)l * 2048 * 2048, q, 1024, 2048, 2048);
    gemm_k<64, 64, 0><<<dim3(8, 16), 256, 0, stream>>>(hn, wk + (size_t)l * 2048 * 512, kb, 1024, 512, 2048);
    gemm_k<64, 64, 2><<<dim3(8, 16), 256, 0, stream>>>(hn, wv + (size_t)l * 2048 * 512, outv_l, 1024, 512, 2048);
    rope_q_kernel<<<4096, 256, 0, stream>>>(q, cosT, sinT);
    rope_k_kernel<<<1024, 256, 0, stream>>>(kb, cosT, sinT, outk_l);
    attn_kernel<<<dim3(32, 32), 256, 0, stream>>>(q, outk_l, outv_l, ctx, flagp);
    gemm_k<128, 64, 1><<<dim3(32, 8), 256, 0, stream>>>(ctx, wo + (size_t)l * 2048 * 2048, h, 1024, 2048, 2048);
    rms_kernel<<<1024, 256, 0, stream>>>(h, ln2 + (size_t)l * 2048, hn);
    gemm_k<128, 128, 0><<<dim3(64, 8), 256, 0, stream>>>(hn, wg + (size_t)l * 2048 * 8192, g, 1024, 8192, 2048);
    gemm_k<128, 128, 0><<<dim3(64, 8), 256, 0, stream>>>(hn, wu + (size_t)l * 2048 * 8192, u, 1024, 8192, 2048);
    silu_kernel<<<8192, 256, 0, stream>>>(g, u, act);
    gemm_k<128, 64, 1><<<dim3(32, 8), 256, 0, stream>>>(act, wd + (size_t)l * 8192 * 2048, h, 1024, 2048, 8192);
  }
  rms_last_kernel<<<1, 256, 0, stream>>>(h, norm_w, hlast);
  gemv_kernel<<<256, 256, 0, stream>>>(hlast, lmh, out);
}